// Round 7
// baseline (157.384 us; speedup 1.0000x reference)
//
#include <hip/hip_runtime.h>
#include <hip/hip_bf16.h>

// Problem constants (B=1)
#define S_LEN 2048
#define E_DIM 1024
#define NH    16
#define HD    64
#define SM_SCALE 0.5f

typedef short bf16x8_t __attribute__((ext_vector_type(8)));   // 8 bf16 = 4 VGPRs
typedef float f32x4_t  __attribute__((ext_vector_type(4)));
typedef __bf16 bf16x4_t __attribute__((ext_vector_type(4)));

static __device__ __forceinline__ unsigned short f2bf_bits(float f) {
    return __builtin_bit_cast(unsigned short, (__bf16)f);
}

// async global->LDS, 16B per lane, dest = wave-uniform base + lane*16
#define GLD16(gp, lp) __builtin_amdgcn_global_load_lds(                       \
    (const __attribute__((address_space(1))) void*)(gp),                      \
    (__attribute__((address_space(3))) void*)(lp), 16, 0, 0)

// -------------------------------------------- merged prep: W^T + x->bf16
__global__ void k_prep(const float* __restrict__ x,
                       const float* __restrict__ Wq, const float* __restrict__ Wk,
                       const float* __restrict__ Wv, const float* __restrict__ Wo,
                       __bf16* __restrict__ xb, __bf16* __restrict__ wt) {
    const int z = blockIdx.z;
    if (z < 4) {
        __shared__ float tile[32][33];
        const float* W = z == 0 ? Wq : z == 1 ? Wk : z == 2 ? Wv : Wo;
        __bf16* o = wt + (size_t)z * E_DIM * E_DIM;
        const int tx = threadIdx.x, ty = threadIdx.y;
        const int bx = blockIdx.x * 32, by = blockIdx.y * 32;
#pragma unroll
        for (int j = 0; j < 32; j += 8)
            tile[ty + j][tx] = W[(size_t)(by + ty + j) * E_DIM + bx + tx];
        __syncthreads();
#pragma unroll
        for (int j = 0; j < 32; j += 8)
            o[(size_t)(bx + ty + j) * E_DIM + by + tx] = (__bf16)tile[tx][ty + j];
    } else {
        const int bid = (z - 4) * 1024 + blockIdx.y * 32 + blockIdx.x;
        const int tid = threadIdx.y * 32 + threadIdx.x;
        const int i = bid * 256 + tid;
        const float4 v = ((const float4*)x)[i];
        bf16x4_t o4;
        o4.x = (__bf16)v.x; o4.y = (__bf16)v.y; o4.z = (__bf16)v.z; o4.w = (__bf16)v.w;
        ((bf16x4_t*)xb)[i] = o4;
    }
}

// ------------------------------------------------------- QKV projection GEMM
// m97-verified 128x128 tile, BK=32: 4 waves, each 4x4 of 16x16x32 MFMA,
// 4 GLD16/thread/step. Epilogue scatters into MFMA-fragment-native layout:
//   Q/K: frag[h][tile s>>6][t=(s>>4)&3][c=d>>5][lane=(d>>3&3)*16+(s&15)][j=d&7]
//   V  : frag[h][tile s>>6][t=d>>4][c=(s>>5)&1][lane=(s>>3&3)*16+(d&15)][j=s&7]
__global__ __launch_bounds__(256) void k_gemm_qkv(
    const __bf16* __restrict__ xb, const __bf16* __restrict__ wt,
    const float* __restrict__ bq, const float* __restrict__ bk, const float* __restrict__ bv,
    __bf16* __restrict__ qkv) {
    __shared__ __align__(16) unsigned short As[128 * 32];
    __shared__ __align__(16) unsigned short Bs[128 * 32];

    const int z = blockIdx.z;
    const __bf16* Bt = wt + (size_t)z * E_DIM * E_DIM;      // W^T [n][k]
    const float* bias = z == 0 ? bq : z == 1 ? bk : bv;
    __bf16* out = qkv + (size_t)z * NH * S_LEN * HD;

    const int tid = threadIdx.x, w = tid >> 6, l = tid & 63;
    const int lm = l & 15, q4 = l >> 4;
    const int bm = blockIdx.y, bn = blockIdx.x;
    const int wm = w >> 1, wn = w & 1;

    // staging: wave w stages rows w*16..+15 and 64+w*16..+15 (lane -> row +l/4, col (l&3)*8)
    const int sm = (w << 4) + (l >> 2);
    const int skk = (l & 3) << 3;
    const __bf16* Ag = xb + (size_t)(bm * 128 + sm) * E_DIM + skk;
    const __bf16* Bg = Bt + (size_t)(bn * 128 + sm) * E_DIM + skk;
    unsigned short* AsW = As + (w << 9);
    unsigned short* BsW = Bs + (w << 9);

    f32x4_t acc[4][4];
#pragma unroll
    for (int i = 0; i < 4; i++)
#pragma unroll
        for (int j = 0; j < 4; j++) { acc[i][j].x = 0.f; acc[i][j].y = 0.f; acc[i][j].z = 0.f; acc[i][j].w = 0.f; }

    for (int k0 = 0; k0 < E_DIM; k0 += 32) {
        __syncthreads();
        GLD16(Ag + k0, AsW);
        GLD16(Ag + (size_t)64 * E_DIM + k0, AsW + 2048);
        GLD16(Bg + k0, BsW);
        GLD16(Bg + (size_t)64 * E_DIM + k0, BsW + 2048);
        __syncthreads();

        bf16x8_t af[4], bfr[4];
#pragma unroll
        for (int mt = 0; mt < 4; mt++)
            af[mt] = *(const bf16x8_t*)&As[(wm * 64 + mt * 16 + lm) * 32 + q4 * 8];
#pragma unroll
        for (int nt = 0; nt < 4; nt++)
            bfr[nt] = *(const bf16x8_t*)&Bs[(wn * 64 + nt * 16 + lm) * 32 + q4 * 8];
#pragma unroll
        for (int mt = 0; mt < 4; mt++)
#pragma unroll
            for (int nt = 0; nt < 4; nt++)
                acc[mt][nt] = __builtin_amdgcn_mfma_f32_16x16x32_bf16(af[mt], bfr[nt], acc[mt][nt], 0, 0, 0);
    }

    // C row s = bm*128 + wm*64 + mt*16 + q4*4 + i ; col n = bn*128 + wn*64 + nt*16 + lm
#pragma unroll
    for (int nt = 0; nt < 4; nt++) {
        const int n = bn * 128 + wn * 64 + nt * 16 + lm;
        const float bval = bias[n];
        const int h = n >> 6, d = n & 63;
        const int tile0 = bm * 2 + wm;      // (row>>6) local: mt*16+q4*4 < 64
        if (z == 2) {
            // V frag-native: t=d>>4, c=mt>>1, lane=(((mt*2+(q4>>1))&3)*16 + d&15), j=(q4&1)*4+i
            const int t4 = d >> 4, flm = d & 15;
#pragma unroll
            for (int mt = 0; mt < 4; mt++) {
                const int q4p = (mt * 2 + (q4 >> 1)) & 3;
                const int j0 = (q4 & 1) * 4;
                __bf16* ob = out + ((((size_t)h * 32 + tile0) * 4 + t4) * 2 + (mt >> 1)) * 512
                                 + (q4p * 16 + flm) * 8 + j0;
                union { unsigned short s[4]; uint2 u; } pk;
#pragma unroll
                for (int i = 0; i < 4; i++) pk.s[i] = f2bf_bits(acc[mt][nt][i] + bval);
                *(uint2*)ob = pk.u;
            }
        } else {
            // Q/K frag-native: t=mt, c=d>>5, lane=((d>>3&3)*16 + s&15), j=d&7
            const float scale = (z == 0) ? SM_SCALE : 1.0f;   // fold SM_SCALE into Q (exact: pow2)
            const int c = d >> 5, q4p = (d >> 3) & 3, j = d & 7;
#pragma unroll
            for (int mt = 0; mt < 4; mt++) {
                __bf16* ob = out + ((((size_t)h * 32 + tile0) * 4 + mt) * 2 + c) * 512
                                 + (q4p * 16 + q4 * 4) * 8 + j;
#pragma unroll
                for (int i = 0; i < 4; i++)
                    ob[i * 8] = (__bf16)((acc[mt][nt][i] + bval) * scale);
            }
        }
    }
}

// ------------------------------------------------------------- attention
// 4 waves x 16 rows, all waves walk the full kt range. K+V tiles (frag-native,
// 8KB each) staged to LDS via GLD16, double-buffered: prefetch next tile
// before computing current, so the end-of-step barrier's vmcnt drain is ~free.
// Transposed-score form: S^T = K·Q^T, O^T = V^T·P. No-max softmax.
__global__ __launch_bounds__(256, 2) void k_attn(
    const __bf16* __restrict__ Qf, const __bf16* __restrict__ Kf, const __bf16* __restrict__ Vf,
    __bf16* __restrict__ attn) {
    __shared__ __align__(16) unsigned short KVs[2][2][4096];  // [buf][K/V][8KB tile]
    __shared__ __align__(16) unsigned short Pl[4][16 * 72];   // per-wave P [row][key]

    // work-balanced swizzle: long q-tiles dispatched first
    const int b = blockIdx.x;
    int qt, h;
    if (b < 256) { qt = 16 + (b >> 4); h = b & 15; }
    else         { qt = 15 - ((b - 256) >> 4); h = (b - 256) & 15; }

    const int tid = threadIdx.x, w = tid >> 6, l = tid & 63;
    const int lm = l & 15, q4 = l >> 4;

    const __bf16* Qb = Qf + ((size_t)h * 32 + qt) * 4096;
    const __bf16* Kb = Kf + (size_t)h * 32 * 4096;
    const __bf16* Vb = Vf + (size_t)h * 32 * 4096;

    // Q B-frags pinned (pre-scaled by SM_SCALE): wave w = row tile t=w
    bf16x8_t qf[2];
#pragma unroll
    for (int c = 0; c < 2; c++)
        qf[c] = *(const bf16x8_t*)(Qb + ((w * 2 + c) << 9) + l * 8);

    float lacc = 0.f;
    f32x4_t oacc[4];   // O^T: per d-tile, lane holds (d=q4*4+i, row=lm)
#pragma unroll
    for (int t = 0; t < 4; t++) { oacc[t].x = 0.f; oacc[t].y = 0.f; oacc[t].z = 0.f; oacc[t].w = 0.f; }

    unsigned short* Pw = Pl[w];

    // prologue: stage tile 0 into buf 0 (wave w: chunks w and w+4 of K and V)
    {
        GLD16(Kb + (w << 9) + l * 8,       &KVs[0][0][(w << 9) + l * 8]);
        GLD16(Kb + ((w + 4) << 9) + l * 8, &KVs[0][0][((w + 4) << 9) + l * 8]);
        GLD16(Vb + (w << 9) + l * 8,       &KVs[0][1][(w << 9) + l * 8]);
        GLD16(Vb + ((w + 4) << 9) + l * 8, &KVs[0][1][((w + 4) << 9) + l * 8]);
    }
    __syncthreads();

    for (int s = 0; s <= qt; s++) {
        const int bb = s & 1;
        if (s < qt) {   // prefetch next tile into the other buffer
            const __bf16* Kg = Kb + (size_t)(s + 1) * 4096;
            const __bf16* Vg = Vb + (size_t)(s + 1) * 4096;
            GLD16(Kg + (w << 9) + l * 8,       &KVs[bb ^ 1][0][(w << 9) + l * 8]);
            GLD16(Kg + ((w + 4) << 9) + l * 8, &KVs[bb ^ 1][0][((w + 4) << 9) + l * 8]);
            GLD16(Vg + (w << 9) + l * 8,       &KVs[bb ^ 1][1][(w << 9) + l * 8]);
            GLD16(Vg + ((w + 4) << 9) + l * 8, &KVs[bb ^ 1][1][((w + 4) << 9) + l * 8]);
        }

        // S^T = K·Q^T : lane holds (key = t*16+q4*4+i, row = lm)
        f32x4_t st[4];
#pragma unroll
        for (int t = 0; t < 4; t++) { st[t].x = 0.f; st[t].y = 0.f; st[t].z = 0.f; st[t].w = 0.f; }
#pragma unroll
        for (int t = 0; t < 4; t++) {
            bf16x8_t kf0 = *(const bf16x8_t*)&KVs[bb][0][((t * 2 + 0) << 9) + l * 8];
            bf16x8_t kf1 = *(const bf16x8_t*)&KVs[bb][0][((t * 2 + 1) << 9) + l * 8];
            st[t] = __builtin_amdgcn_mfma_f32_16x16x32_bf16(kf0, qf[0], st[t], 0, 0, 0);
            st[t] = __builtin_amdgcn_mfma_f32_16x16x32_bf16(kf1, qf[1], st[t], 0, 0, 0);
        }
        // P = exp(S); causal mask only on diagonal tile (local coords suffice)
        if (s == qt) {
            const int rowl = w * 16 + lm;
#pragma unroll
            for (int t = 0; t < 4; t++)
#pragma unroll
                for (int i = 0; i < 4; i++) {
                    const int keyl = t * 16 + q4 * 4 + i;
                    st[t][i] = (keyl > rowl) ? 0.f : __expf(st[t][i]);
                }
        } else {
#pragma unroll
            for (int t = 0; t < 4; t++)
#pragma unroll
                for (int i = 0; i < 4; i++) st[t][i] = __expf(st[t][i]);
        }
#pragma unroll
        for (int t = 0; t < 4; t++)
            lacc += (st[t][0] + st[t][1]) + (st[t][2] + st[t][3]);
        // P-write: 4 consecutive keys per lane -> one b64 per t (wave-private)
#pragma unroll
        for (int t = 0; t < 4; t++) {
            union { unsigned short s4[4]; uint2 u; } pk;
#pragma unroll
            for (int i = 0; i < 4; i++) pk.s4[i] = f2bf_bits(st[t][i]);
            *(uint2*)&Pw[lm * 72 + t * 16 + q4 * 4] = pk.u;
        }
        // O^T += V^T·P : A = V frags (LDS), B = P frags (wave-private LDS)
#pragma unroll
        for (int c = 0; c < 2; c++) {
            bf16x8_t pf = *(const bf16x8_t*)&Pw[lm * 72 + c * 32 + q4 * 8];
#pragma unroll
            for (int t = 0; t < 4; t++) {
                bf16x8_t vf = *(const bf16x8_t*)&KVs[bb][1][((t * 2 + c) << 9) + l * 8];
                oacc[t] = __builtin_amdgcn_mfma_f32_16x16x32_bf16(vf, pf, oacc[t], 0, 0, 0);
            }
        }
        __syncthreads();   // all reads of buf bb done; prefetch of bb^1 landed
    }

    // l-reduction: row lm's partials live in lanes lm, lm+16, lm+32, lm+48
    lacc += __shfl_xor(lacc, 16, 64);
    lacc += __shfl_xor(lacc, 32, 64);
    const float rl = 1.f / lacc;
    const int row = qt * 64 + w * 16 + lm;
#pragma unroll
    for (int t = 0; t < 4; t++) {
        union { unsigned short s4[4]; uint2 u; } pk;
#pragma unroll
        for (int i = 0; i < 4; i++) pk.s4[i] = f2bf_bits(oacc[t][i] * rl);
        *(uint2*)(attn + (size_t)row * E_DIM + h * HD + t * 16 + q4 * 4) = pk.u;
    }
}

// --------------------------------------------------------- output projection
// 64x128 tile, grid 256 = 1 block/CU -> staging latency fully exposed without
// co-resident blocks; double-buffer the LDS tiles (prefetch-then-compute).
__global__ __launch_bounds__(256) void k_gemm_out(
    const __bf16* __restrict__ A, const __bf16* __restrict__ Bt,
    const float* __restrict__ bias, float* __restrict__ out) {
    __shared__ __align__(16) unsigned short As[2][64 * 32];
    __shared__ __align__(16) unsigned short Bs[2][128 * 32];

    const int tid = threadIdx.x, w = tid >> 6, l = tid & 63;
    const int lm = l & 15, q4 = l >> 4;
    const int bm = blockIdx.y, bn = blockIdx.x;
    const int wm = w >> 1, wn = w & 1;

    const int sm = (w << 4) + (l >> 2);
    const int skk = (l & 3) << 3;
    const __bf16* Ag = A + (size_t)(bm * 64 + sm) * E_DIM + skk;
    const __bf16* Bg = Bt + (size_t)(bn * 128 + sm) * E_DIM + skk;
    const int woff = w << 9;

    f32x4_t acc[2][4];
#pragma unroll
    for (int i = 0; i < 2; i++)
#pragma unroll
        for (int j = 0; j < 4; j++) { acc[i][j].x = 0.f; acc[i][j].y = 0.f; acc[i][j].z = 0.f; acc[i][j].w = 0.f; }

    // prologue: stage k-tile 0 into buf 0
    GLD16(Ag, &As[0][woff]);
    GLD16(Bg, &Bs[0][woff]);
    GLD16(Bg + (size_t)64 * E_DIM, &Bs[0][woff + 2048]);
    __syncthreads();

    for (int s = 0; s < 32; s++) {
        const int bb = s & 1;
        if (s < 31) {   // prefetch next k-tile
            const int k0 = (s + 1) * 32;
            GLD16(Ag + k0, &As[bb ^ 1][woff]);
            GLD16(Bg + k0, &Bs[bb ^ 1][woff]);
            GLD16(Bg + (size_t)64 * E_DIM + k0, &Bs[bb ^ 1][woff + 2048]);
        }

        bf16x8_t af[2], bfr[4];
#pragma unroll
        for (int mt = 0; mt < 2; mt++)
            af[mt] = *(const bf16x8_t*)&As[bb][(wm * 32 + mt * 16 + lm) * 32 + q4 * 8];
#pragma unroll
        for (int nt = 0; nt < 4; nt++)
            bfr[nt] = *(const bf16x8_t*)&Bs[bb][(wn * 64 + nt * 16 + lm) * 32 + q4 * 8];
#pragma unroll
        for (int mt = 0; mt < 2; mt++)
#pragma unroll
            for (int nt = 0; nt < 4; nt++)
                acc[mt][nt] = __builtin_amdgcn_mfma_f32_16x16x32_bf16(af[mt], bfr[nt], acc[mt][nt], 0, 0, 0);
        __syncthreads();   // reads of bb done; prefetch into bb^1 landed
    }

#pragma unroll
    for (int nt = 0; nt < 4; nt++) {
        const int n = bn * 128 + wn * 64 + nt * 16 + lm;
        const float bval = bias[n];
#pragma unroll
        for (int mt = 0; mt < 2; mt++) {
            const int r0 = bm * 64 + wm * 32 + mt * 16 + q4 * 4;
#pragma unroll
            for (int i = 0; i < 4; i++)
                out[(size_t)(r0 + i) * E_DIM + n] = acc[mt][nt][i] + bval;
        }
    }
}

extern "C" void kernel_launch(void* const* d_in, const int* in_sizes, int n_in,
                              void* d_out, int out_size, void* d_ws, size_t ws_size,
                              hipStream_t stream) {
    const float* x  = (const float*)d_in[0];
    const float* Wq = (const float*)d_in[1];
    const float* bq = (const float*)d_in[2];
    const float* Wk = (const float*)d_in[3];
    const float* bk = (const float*)d_in[4];
    const float* Wv = (const float*)d_in[5];
    const float* bv = (const float*)d_in[6];
    const float* Wo = (const float*)d_in[7];
    const float* bo = (const float*)d_in[8];
    float* out = (float*)d_out;

    char* ws = (char*)d_ws;
    __bf16* xb   = (__bf16*)(ws);                        // 4 MB  x bf16 [S][E]
    __bf16* wt   = (__bf16*)(ws + ((size_t)4  << 20));   // 4x2MB [Wq^T,Wk^T,Wv^T,Wo^T] bf16
    __bf16* qkv  = (__bf16*)(ws + ((size_t)12 << 20));   // frag-native Qf,Kf,Vf (4MB each)
    __bf16* attn = (__bf16*)(ws + ((size_t)24 << 20));   // 4 MB  [S][E] bf16

    k_prep<<<dim3(32, 32, 6), dim3(32, 8), 0, stream>>>(x, Wq, Wk, Wv, Wo, xb, wt);
    k_gemm_qkv<<<dim3(E_DIM / 128, S_LEN / 128, 3), 256, 0, stream>>>(xb, wt, bq, bk, bv, qkv);
    k_attn<<<dim3(512), 256, 0, stream>>>(
        qkv, qkv + (size_t)NH * S_LEN * HD, qkv + (size_t)2 * NH * S_LEN * HD, attn);
    k_gemm_out<<<dim3(E_DIM / 128, S_LEN / 64), 256, 0, stream>>>(
        attn, wt + (size_t)3 * E_DIM * E_DIM, bo, out);
}

// Round 8
// 154.467 us; speedup vs baseline: 1.0189x; 1.0189x over previous
//
#include <hip/hip_runtime.h>
#include <hip/hip_bf16.h>

// Problem constants (B=1)
#define S_LEN 2048
#define E_DIM 1024
#define NH    16
#define HD    64
#define SM_SCALE 0.5f

typedef short bf16x8_t  __attribute__((ext_vector_type(8)));    // 8 bf16 = 4 VGPRs
typedef float f32x4_t   __attribute__((ext_vector_type(4)));
typedef float f32x16_t  __attribute__((ext_vector_type(16)));
typedef __bf16 bf16x4_t __attribute__((ext_vector_type(4)));

static __device__ __forceinline__ unsigned short f2bf_bits(float f) {
    return __builtin_bit_cast(unsigned short, (__bf16)f);
}

// async global->LDS, 16B per lane, dest = wave-uniform base + lane*16
#define GLD16(gp, lp) __builtin_amdgcn_global_load_lds(                       \
    (const __attribute__((address_space(1))) void*)(gp),                      \
    (__attribute__((address_space(3))) void*)(lp), 16, 0, 0)

// -------------------------------------------- merged prep: W^T + x->bf16
__global__ void k_prep(const float* __restrict__ x,
                       const float* __restrict__ Wq, const float* __restrict__ Wk,
                       const float* __restrict__ Wv, const float* __restrict__ Wo,
                       __bf16* __restrict__ xb, __bf16* __restrict__ wt) {
    const int z = blockIdx.z;
    if (z < 4) {
        __shared__ float tile[32][33];
        const float* W = z == 0 ? Wq : z == 1 ? Wk : z == 2 ? Wv : Wo;
        __bf16* o = wt + (size_t)z * E_DIM * E_DIM;
        const int tx = threadIdx.x, ty = threadIdx.y;
        const int bx = blockIdx.x * 32, by = blockIdx.y * 32;
#pragma unroll
        for (int j = 0; j < 32; j += 8)
            tile[ty + j][tx] = W[(size_t)(by + ty + j) * E_DIM + bx + tx];
        __syncthreads();
#pragma unroll
        for (int j = 0; j < 32; j += 8)
            o[(size_t)(bx + ty + j) * E_DIM + by + tx] = (__bf16)tile[tx][ty + j];
    } else {
        const int bid = (z - 4) * 1024 + blockIdx.y * 32 + blockIdx.x;
        const int tid = threadIdx.y * 32 + threadIdx.x;
        const int i = bid * 256 + tid;
        const float4 v = ((const float4*)x)[i];
        bf16x4_t o4;
        o4.x = (__bf16)v.x; o4.y = (__bf16)v.y; o4.z = (__bf16)v.z; o4.w = (__bf16)v.w;
        ((bf16x4_t*)xb)[i] = o4;
    }
}

// ------------------------------------------------------- QKV projection GEMM
// 128x128 tile, BK=32 (m97 structure). Epilogue scatters into 32x32x16-MFMA
// operand-native layout (A/B layout: [m|n=lane&31][k=(lane>>5)*8+j]):
//   Q (B-op): [h][qt][rb2][kc4][lane64][j8]  rb=(s&63)>>5, lane=(s&31)+((d>>3)&1)*32, kc=d>>4, j=d&7
//   K (A-op): same index function as Q
//   V (A-op, V^T): [h][kt][db2][kc4][lane64][j8] db=d>>5, lane=(d&31)+((key>>3)&1)*32, kc=(key&63)>>4, j=key&7
__global__ __launch_bounds__(256) void k_gemm_qkv(
    const __bf16* __restrict__ xb, const __bf16* __restrict__ wt,
    const float* __restrict__ bq, const float* __restrict__ bk, const float* __restrict__ bv,
    __bf16* __restrict__ qkv) {
    __shared__ __align__(16) unsigned short As[128 * 32];
    __shared__ __align__(16) unsigned short Bs[128 * 32];

    const int z = blockIdx.z;
    const __bf16* Bt = wt + (size_t)z * E_DIM * E_DIM;      // W^T [n][k]
    const float* bias = z == 0 ? bq : z == 1 ? bk : bv;
    __bf16* out = qkv + (size_t)z * NH * S_LEN * HD;

    const int tid = threadIdx.x, w = tid >> 6, l = tid & 63;
    const int lm = l & 15, q4 = l >> 4;
    const int bm = blockIdx.y, bn = blockIdx.x;
    const int wm = w >> 1, wn = w & 1;

    const int sm = (w << 4) + (l >> 2);
    const int skk = (l & 3) << 3;
    const __bf16* Ag = xb + (size_t)(bm * 128 + sm) * E_DIM + skk;
    const __bf16* Bg = Bt + (size_t)(bn * 128 + sm) * E_DIM + skk;
    unsigned short* AsW = As + (w << 9);
    unsigned short* BsW = Bs + (w << 9);

    f32x4_t acc[4][4];
#pragma unroll
    for (int i = 0; i < 4; i++)
#pragma unroll
        for (int j = 0; j < 4; j++) { acc[i][j].x = 0.f; acc[i][j].y = 0.f; acc[i][j].z = 0.f; acc[i][j].w = 0.f; }

    for (int k0 = 0; k0 < E_DIM; k0 += 32) {
        __syncthreads();
        GLD16(Ag + k0, AsW);
        GLD16(Ag + (size_t)64 * E_DIM + k0, AsW + 2048);
        GLD16(Bg + k0, BsW);
        GLD16(Bg + (size_t)64 * E_DIM + k0, BsW + 2048);
        __syncthreads();

        bf16x8_t af[4], bfr[4];
#pragma unroll
        for (int mt = 0; mt < 4; mt++)
            af[mt] = *(const bf16x8_t*)&As[(wm * 64 + mt * 16 + lm) * 32 + q4 * 8];
#pragma unroll
        for (int nt = 0; nt < 4; nt++)
            bfr[nt] = *(const bf16x8_t*)&Bs[(wn * 64 + nt * 16 + lm) * 32 + q4 * 8];
#pragma unroll
        for (int mt = 0; mt < 4; mt++)
#pragma unroll
            for (int nt = 0; nt < 4; nt++)
                acc[mt][nt] = __builtin_amdgcn_mfma_f32_16x16x32_bf16(af[mt], bfr[nt], acc[mt][nt], 0, 0, 0);
    }

    // C row s = bm*128 + wm*64 + mt*16 + q4*4 + i ; col n = bn*128 + wn*64 + nt*16 + lm
#pragma unroll
    for (int nt = 0; nt < 4; nt++) {
        const int n = bn * 128 + wn * 64 + nt * 16 + lm;
        const float bval = bias[n];
        const int h = n >> 6, d = n & 63;
        const int tile0 = bm * 2 + wm;          // s>>6
        if (z == 2) {
            // V A-op-native: key = mt*16 + q4*4 + i (local in tile)
            const int db = d >> 5, dl = d & 31;
#pragma unroll
            for (int mt = 0; mt < 4; mt++) {
                __bf16* ob = out + (((size_t)h * 32 + tile0) * 8 + db * 4 + mt) * 512
                                 + (dl + (q4 >> 1) * 32) * 8 + (q4 & 1) * 4;
                union { unsigned short s4[4]; uint2 u; } pk;
#pragma unroll
                for (int i = 0; i < 4; i++) pk.s4[i] = f2bf_bits(acc[mt][nt][i] + bval);
                *(uint2*)ob = pk.u;
            }
        } else {
            // Q/K op-native: s_local = mt*16 + q4*4 + i, rb = mt>>1
            const float scale = (z == 0) ? SM_SCALE : 1.0f;   // fold SM_SCALE into Q (exact: pow2)
            const int kc = d >> 4, khalf = (d >> 3) & 1, j = d & 7;
#pragma unroll
            for (int mt = 0; mt < 4; mt++) {
                __bf16* ob = out + (((size_t)h * 32 + tile0) * 8 + (mt >> 1) * 4 + kc) * 512
                                 + ((mt & 1) * 16 + q4 * 4 + khalf * 32) * 8 + j;
#pragma unroll
                for (int i = 0; i < 4; i++)
                    ob[i * 8] = (__bf16)((acc[mt][nt][i] + bval) * scale);
            }
        }
    }
}

// ------------------------------------------------------------- attention
// 32x32x16 MFMA. 4 waves = (row-half rh = w&1) x (key-half kh = w>>1).
// Wave (rh,kh): S^T(32k x 32r) = K_kh · Q_rh^T in 4 MFMA (4 kf b128 reads),
// O^T(64d x 32r) += V^T·P in 4 MFMA (4 vf + 2 pf reads). Halves LDS traffic
// per covered area vs 16x16 form. Key-half partials combine linearly at end
// (no-max softmax, scores bounded). K/V tiles double-buffered via GLD16.
__global__ __launch_bounds__(256, 2) void k_attn(
    const __bf16* __restrict__ Qf, const __bf16* __restrict__ Kf, const __bf16* __restrict__ Vf,
    __bf16* __restrict__ attn) {
    __shared__ __align__(16) unsigned short KVs[2][2][4096];  // [buf][K/V][8KB tile]
    __shared__ __align__(16) unsigned short Pl[4][32 * 40];   // per-wave P [row][key] pad 40

    // work-balanced swizzle: long q-tiles dispatched first
    const int b = blockIdx.x;
    int qt, h;
    if (b < 256) { qt = 16 + (b >> 4); h = b & 15; }
    else         { qt = 15 - ((b - 256) >> 4); h = (b - 256) & 15; }

    const int tid = threadIdx.x, w = tid >> 6, l = tid & 63;
    const int rh = w & 1, kh = w >> 1;
    const int l31 = l & 31, lh = l >> 5;

    const __bf16* Qb = Qf + ((size_t)h * 32 + qt) * 4096;
    const __bf16* Kb = Kf + (size_t)h * 32 * 4096;
    const __bf16* Vb = Vf + (size_t)h * 32 * 4096;

    // Q B-frags pinned (pre-scaled by SM_SCALE): rows rh*32..+31, 4 k-chunks
    bf16x8_t qf[4];
#pragma unroll
    for (int kc = 0; kc < 4; kc++)
        qf[kc] = *(const bf16x8_t*)(Qb + ((rh * 4 + kc) << 9) + l * 8);

    float lacc = 0.f;
    f32x16_t oacc[2];
#pragma unroll
    for (int db = 0; db < 2; db++)
#pragma unroll
        for (int r = 0; r < 16; r++) oacc[db][r] = 0.f;

    unsigned short* Pw = Pl[w];

    // prologue: stage tile 0 into buf 0 (wave w: chunks w, w+4 of K and V)
    GLD16(Kb + (w << 9) + l * 8,       &KVs[0][0][(w << 9) + l * 8]);
    GLD16(Kb + ((w + 4) << 9) + l * 8, &KVs[0][0][((w + 4) << 9) + l * 8]);
    GLD16(Vb + (w << 9) + l * 8,       &KVs[0][1][(w << 9) + l * 8]);
    GLD16(Vb + ((w + 4) << 9) + l * 8, &KVs[0][1][((w + 4) << 9) + l * 8]);
    __syncthreads();

    for (int s = 0; s <= qt; s++) {
        const int bb = s & 1;
        if (s < qt) {   // prefetch next tile into the other buffer
            const __bf16* Kg = Kb + (size_t)(s + 1) * 4096;
            const __bf16* Vg = Vb + (size_t)(s + 1) * 4096;
            GLD16(Kg + (w << 9) + l * 8,       &KVs[bb ^ 1][0][(w << 9) + l * 8]);
            GLD16(Kg + ((w + 4) << 9) + l * 8, &KVs[bb ^ 1][0][((w + 4) << 9) + l * 8]);
            GLD16(Vg + (w << 9) + l * 8,       &KVs[bb ^ 1][1][(w << 9) + l * 8]);
            GLD16(Vg + ((w + 4) << 9) + l * 8, &KVs[bb ^ 1][1][((w + 4) << 9) + l * 8]);
        }

        const bool diag = (s == qt);
        if (!(diag && kh > rh)) {          // (rh=0,kh=1) diag block fully masked
            // S^T = K·Q^T : D[key = (reg&3)+8*(reg>>2)+4*lh][row = l31]
            f32x16_t st;
#pragma unroll
            for (int r = 0; r < 16; r++) st[r] = 0.f;
#pragma unroll
            for (int kc = 0; kc < 4; kc++) {
                bf16x8_t kf = *(const bf16x8_t*)&KVs[bb][0][((kh * 4 + kc) << 9) + l * 8];
                st = __builtin_amdgcn_mfma_f32_32x32x16_bf16(kf, qf[kc], st, 0, 0, 0);
            }
            // exp (+ causal mask only on the diagonal kh==rh block)
            if (diag && kh == rh) {
#pragma unroll
                for (int r = 0; r < 16; r++) {
                    const int keyl = (r & 3) + 8 * (r >> 2) + 4 * lh;
                    st[r] = (keyl > l31) ? 0.f : __expf(st[r]);
                }
            } else {
#pragma unroll
                for (int r = 0; r < 16; r++) st[r] = __expf(st[r]);
            }
#pragma unroll
            for (int r = 0; r < 16; r++) lacc += st[r];
            // P write: reg-quad a holds keys 8a+4lh+[0..3] for row l31 -> b64
#pragma unroll
            for (int a = 0; a < 4; a++) {
                union { unsigned short s4[4]; uint2 u; } pk;
#pragma unroll
                for (int i = 0; i < 4; i++) pk.s4[i] = f2bf_bits(st[a * 4 + i]);
                *(uint2*)&Pw[l31 * 40 + lh * 4 + a * 8] = pk.u;
            }
            // O^T += V^T·P : A = V frags, B = P frags (keys kh*32 + c*16 + lh*8 + j)
#pragma unroll
            for (int c = 0; c < 2; c++) {
                bf16x8_t pf = *(const bf16x8_t*)&Pw[l31 * 40 + c * 16 + lh * 8];
#pragma unroll
                for (int db = 0; db < 2; db++) {
                    bf16x8_t vf = *(const bf16x8_t*)&KVs[bb][1][((db * 4 + kh * 2 + c) << 9) + l * 8];
                    oacc[db] = __builtin_amdgcn_mfma_f32_32x32x16_bf16(vf, pf, oacc[db], 0, 0, 0);
                }
            }
        }
        __syncthreads();   // reads of buf bb done; prefetch of bb^1 landed
    }

    // ---- key-half combine (linear: no-max softmax) ----
    __syncthreads();                        // KVs reusable as exchange space
    float* Ex = (float*)KVs;                // [rh*64 + lane][34]: 32 O + lacc
    if (kh == 1) {
        float* e = Ex + (rh * 64 + l) * 34;
#pragma unroll
        for (int db = 0; db < 2; db++)
#pragma unroll
            for (int r = 0; r < 16; r++) e[db * 16 + r] = oacc[db][r];
        e[32] = lacc;
    }
    __syncthreads();
    if (kh == 0) {
        const float* e = Ex + (rh * 64 + l) * 34;
#pragma unroll
        for (int db = 0; db < 2; db++)
#pragma unroll
            for (int r = 0; r < 16; r++) oacc[db][r] += e[db * 16 + r];
        lacc += e[32];
        lacc += __shfl_xor(lacc, 32, 64);   // lanes l31 / l31+32 hold same row
        const float rl = 1.f / lacc;
        const int row = qt * 64 + rh * 32 + l31;
#pragma unroll
        for (int db = 0; db < 2; db++)
#pragma unroll
            for (int a = 0; a < 4; a++) {
                union { unsigned short s4[4]; uint2 u; } pk;
#pragma unroll
                for (int i = 0; i < 4; i++) pk.s4[i] = f2bf_bits(oacc[db][a * 4 + i] * rl);
                *(uint2*)(attn + (size_t)row * E_DIM + h * HD + db * 32 + a * 8 + lh * 4) = pk.u;
            }
    }
}

// --------------------------------------------------------- output projection
// 64x128 tile, double-buffered LDS staging (1 block/CU -> latency exposed).
__global__ __launch_bounds__(256) void k_gemm_out(
    const __bf16* __restrict__ A, const __bf16* __restrict__ Bt,
    const float* __restrict__ bias, float* __restrict__ out) {
    __shared__ __align__(16) unsigned short As[2][64 * 32];
    __shared__ __align__(16) unsigned short Bs[2][128 * 32];

    const int tid = threadIdx.x, w = tid >> 6, l = tid & 63;
    const int lm = l & 15, q4 = l >> 4;
    const int bm = blockIdx.y, bn = blockIdx.x;
    const int wm = w >> 1, wn = w & 1;

    const int sm = (w << 4) + (l >> 2);
    const int skk = (l & 3) << 3;
    const __bf16* Ag = A + (size_t)(bm * 64 + sm) * E_DIM + skk;
    const __bf16* Bg = Bt + (size_t)(bn * 128 + sm) * E_DIM + skk;
    const int woff = w << 9;

    f32x4_t acc[2][4];
#pragma unroll
    for (int i = 0; i < 2; i++)
#pragma unroll
        for (int j = 0; j < 4; j++) { acc[i][j].x = 0.f; acc[i][j].y = 0.f; acc[i][j].z = 0.f; acc[i][j].w = 0.f; }

    GLD16(Ag, &As[0][woff]);
    GLD16(Bg, &Bs[0][woff]);
    GLD16(Bg + (size_t)64 * E_DIM, &Bs[0][woff + 2048]);
    __syncthreads();

    for (int s = 0; s < 32; s++) {
        const int bb = s & 1;
        if (s < 31) {
            const int k0 = (s + 1) * 32;
            GLD16(Ag + k0, &As[bb ^ 1][woff]);
            GLD16(Bg + k0, &Bs[bb ^ 1][woff]);
            GLD16(Bg + (size_t)64 * E_DIM + k0, &Bs[bb ^ 1][woff + 2048]);
        }

        bf16x8_t af[2], bfr[4];
#pragma unroll
        for (int mt = 0; mt < 2; mt++)
            af[mt] = *(const bf16x8_t*)&As[bb][(wm * 32 + mt * 16 + lm) * 32 + q4 * 8];
#pragma unroll
        for (int nt = 0; nt < 4; nt++)
            bfr[nt] = *(const bf16x8_t*)&Bs[bb][(wn * 64 + nt * 16 + lm) * 32 + q4 * 8];
#pragma unroll
        for (int mt = 0; mt < 2; mt++)
#pragma unroll
            for (int nt = 0; nt < 4; nt++)
                acc[mt][nt] = __builtin_amdgcn_mfma_f32_16x16x32_bf16(af[mt], bfr[nt], acc[mt][nt], 0, 0, 0);
        __syncthreads();
    }

#pragma unroll
    for (int nt = 0; nt < 4; nt++) {
        const int n = bn * 128 + wn * 64 + nt * 16 + lm;
        const float bval = bias[n];
#pragma unroll
        for (int mt = 0; mt < 2; mt++) {
            const int r0 = bm * 64 + wm * 32 + mt * 16 + q4 * 4;
#pragma unroll
            for (int i = 0; i < 4; i++)
                out[(size_t)(r0 + i) * E_DIM + n] = acc[mt][nt][i] + bval;
        }
    }
}

extern "C" void kernel_launch(void* const* d_in, const int* in_sizes, int n_in,
                              void* d_out, int out_size, void* d_ws, size_t ws_size,
                              hipStream_t stream) {
    const float* x  = (const float*)d_in[0];
    const float* Wq = (const float*)d_in[1];
    const float* bq = (const float*)d_in[2];
    const float* Wk = (const float*)d_in[3];
    const float* bk = (const float*)d_in[4];
    const float* Wv = (const float*)d_in[5];
    const float* bv = (const float*)d_in[6];
    const float* Wo = (const float*)d_in[7];
    const float* bo = (const float*)d_in[8];
    float* out = (float*)d_out;

    char* ws = (char*)d_ws;
    __bf16* xb   = (__bf16*)(ws);                        // 4 MB  x bf16 [S][E]
    __bf16* wt   = (__bf16*)(ws + ((size_t)4  << 20));   // 4x2MB [Wq^T,Wk^T,Wv^T,Wo^T] bf16
    __bf16* qkv  = (__bf16*)(ws + ((size_t)12 << 20));   // op-native Qf,Kf,Vf (4MB each)
    __bf16* attn = (__bf16*)(ws + ((size_t)24 << 20));   // 4 MB  [S][E] bf16

    k_prep<<<dim3(32, 32, 6), dim3(32, 8), 0, stream>>>(x, Wq, Wk, Wv, Wo, xb, wt);
    k_gemm_qkv<<<dim3(E_DIM / 128, S_LEN / 128, 3), 256, 0, stream>>>(xb, wt, bq, bk, bv, qkv);
    k_attn<<<dim3(512), 256, 0, stream>>>(
        qkv, qkv + (size_t)NH * S_LEN * HD, qkv + (size_t)2 * NH * S_LEN * HD, attn);
    k_gemm_out<<<dim3(E_DIM / 128, S_LEN / 64), 256, 0, stream>>>(
        attn, wt + (size_t)3 * E_DIM * E_DIM, bo, out);
}